// Round 1
// baseline (62.448 us; speedup 1.0000x reference)
//
#include <hip/hip_runtime.h>

#define N 8192

using f4 = __attribute__((ext_vector_type(4))) float;

__global__ __launch_bounds__(256) void proj_kernel(
    const float* __restrict__ q, const float* __restrict__ k, const float* __restrict__ v,
    const float* __restrict__ Wq, const float* __restrict__ bq,
    const float* __restrict__ Wk, const float* __restrict__ bk,
    const float* __restrict__ Wv, const float* __restrict__ bv,
    float* __restrict__ aq, float* __restrict__ kp, float* __restrict__ vp)
{
    const int tn = threadIdx.x & 63;
    const int tb = threadIdx.x >> 6;        // 0..3, splits the B=64 reduction
    const int n  = blockIdx.x * 64 + tn;
    float sq = 0.f, sk = 0.f, sv = 0.f;
#pragma unroll
    for (int bi = 0; bi < 16; ++bi) {
        const int b = tb * 16 + bi;
        sq = fmaf(q[b * N + n], Wq[b], sq);
        sk = fmaf(k[b * N + n], Wk[b], sk);
        sv = fmaf(v[b * N + n], Wv[b], sv);
    }
    __shared__ float red[3][4][64];
    red[0][tb][tn] = sq; red[1][tb][tn] = sk; red[2][tb][tn] = sv;
    __syncthreads();
    if (tb == 0) {
        const float fq = red[0][0][tn] + red[0][1][tn] + red[0][2][tn] + red[0][3][tn];
        const float fk = red[1][0][tn] + red[1][1][tn] + red[1][2][tn] + red[1][3][tn];
        const float fv = red[2][0][tn] + red[2][1][tn] + red[2][2][tn] + red[2][3][tn];
        aq[n] = (fq + bq[0]) * 0.125f;   // fold in 1/sqrt(dk) = 1/8
        kp[n] = fk + bk[0];
        vp[n] = fv + bv[0];
    }
}

__global__ __launch_bounds__(512) void attn_kernel(
    const float* __restrict__ aq, const float* __restrict__ kp, const float* __restrict__ vp,
    float* __restrict__ out, float* __restrict__ attn)
{
    __shared__ float kl[N];
    __shared__ float vl[N];
    __shared__ float wmax[8], wmin[8];
    const int tid  = threadIdx.x;
    const int lane = tid & 63;
    const int wave = tid >> 6;              // 0..7

    // Stage kp, vp into LDS; track block-local min/max of kp.
    float lmax = -1e30f, lmin = 1e30f;
#pragma unroll
    for (int it = 0; it < 4; ++it) {
        const int i4 = tid + it * 512;      // float4 index, 2048 total
        const f4 kk = reinterpret_cast<const f4*>(kp)[i4];
        const f4 vv = reinterpret_cast<const f4*>(vp)[i4];
        reinterpret_cast<f4*>(kl)[i4] = kk;
        reinterpret_cast<f4*>(vl)[i4] = vv;
        lmax = fmaxf(lmax, fmaxf(fmaxf(kk[0], kk[1]), fmaxf(kk[2], kk[3])));
        lmin = fminf(lmin, fminf(fminf(kk[0], kk[1]), fminf(kk[2], kk[3])));
    }
#pragma unroll
    for (int off = 32; off; off >>= 1) {
        lmax = fmaxf(lmax, __shfl_xor(lmax, off));
        lmin = fminf(lmin, __shfl_xor(lmin, off));
    }
    if (lane == 0) { wmax[wave] = lmax; wmin[wave] = lmin; }
    __syncthreads();
    float kmax = wmax[0], kmin = wmin[0];
#pragma unroll
    for (int w = 1; w < 8; ++w) { kmax = fmaxf(kmax, wmax[w]); kmin = fminf(kmin, wmin[w]); }

    // Each wave owns 2 rows; no block barriers below, so waves drift and
    // the store stream stays continuously busy.
    for (int rr = 0; rr < 2; ++rr) {
        const int r = blockIdx.x * 16 + wave * 2 + rr;
        const float a = aq[r];                               // scale already folded in
        const float m = (a >= 0.f) ? a * kmax : a * kmin;    // true row max
        float s = 0.f, o = 0.f;
#pragma unroll 8
        for (int it = 0; it < 32; ++it) {
            const f4 kk = reinterpret_cast<const f4*>(kl)[lane + it * 64];
            const f4 vv = reinterpret_cast<const f4*>(vl)[lane + it * 64];
            const float e0 = __expf(fmaf(a, kk[0], -m));
            const float e1 = __expf(fmaf(a, kk[1], -m));
            const float e2 = __expf(fmaf(a, kk[2], -m));
            const float e3 = __expf(fmaf(a, kk[3], -m));
            s += (e0 + e1) + (e2 + e3);
            o = fmaf(e0, vv[0], o);
            o = fmaf(e1, vv[1], o);
            o = fmaf(e2, vv[2], o);
            o = fmaf(e3, vv[3], o);
        }
#pragma unroll
        for (int off = 32; off; off >>= 1) {
            s += __shfl_xor(s, off);
            o += __shfl_xor(o, off);
        }
        const float inv = 1.0f / s;
        if (lane == 0) out[r] = o * inv;

        f4* __restrict__ arow = reinterpret_cast<f4*>(attn + (size_t)r * N);
#pragma unroll 8
        for (int it = 0; it < 32; ++it) {
            const f4 kk = reinterpret_cast<const f4*>(kl)[lane + it * 64];
            f4 e;
            e[0] = __expf(fmaf(a, kk[0], -m)) * inv;
            e[1] = __expf(fmaf(a, kk[1], -m)) * inv;
            e[2] = __expf(fmaf(a, kk[2], -m)) * inv;
            e[3] = __expf(fmaf(a, kk[3], -m)) * inv;
            __builtin_nontemporal_store(e, &arow[lane + it * 64]);
        }
    }
}

extern "C" void kernel_launch(void* const* d_in, const int* in_sizes, int n_in,
                              void* d_out, int out_size, void* d_ws, size_t ws_size,
                              hipStream_t stream)
{
    const float* q  = (const float*)d_in[0];
    const float* k  = (const float*)d_in[1];
    const float* v  = (const float*)d_in[2];
    const float* Wq = (const float*)d_in[3];
    const float* bq = (const float*)d_in[4];
    const float* Wk = (const float*)d_in[5];
    const float* bk = (const float*)d_in[6];
    const float* Wv = (const float*)d_in[7];
    const float* bv = (const float*)d_in[8];

    float* out  = (float*)d_out;       // [N]  (first output)
    float* attn = out + N;             // [N,N] (second output)

    float* aq = (float*)d_ws;          // qp * 1/8
    float* kp = aq + N;
    float* vp = kp + N;

    proj_kernel<<<128, 256, 0, stream>>>(q, k, v, Wq, bq, Wk, bk, Wv, bv, aq, kp, vp);
    attn_kernel<<<512, 512, 0, stream>>>(aq, kp, vp, out, attn);
}